// Round 3
// baseline (397.991 us; speedup 1.0000x reference)
//
#include <hip/hip_runtime.h>
#include <hip/hip_bf16.h>
#include <math.h>

#define N 8192
#define D 1024
#define TILE 128
#define NTILES (N / TILE)                 // 64
#define NBLOCKS (NTILES * (NTILES + 1) / 2)  // 2080 lower-tri tiles

typedef __bf16 bf16_t;
typedef bf16_t bf16x4 __attribute__((ext_vector_type(4)));
typedef bf16_t bf16x8 __attribute__((ext_vector_type(8)));
typedef float f32x4 __attribute__((ext_vector_type(4)));

// exp(sim/T) = exp2(sim * 1/(T*ln2)); we fold sqrt(1/(T*ln2)) = 4.5398124
// into the normalized embeddings so the GEMM accumulator is already the
// exp2 argument and the epilogue is a single v_exp_f32 per element.
#define POST_SCALE 4.5398124f

// ---------------------------------------------------------------------------
// Kernel 1: L2-normalize rows, scale by POST_SCALE, cast to bf16.
// ---------------------------------------------------------------------------
__global__ __launch_bounds__(256) void norm_cast(const float* __restrict__ in,
                                                 bf16_t* __restrict__ out) {
    const int row = blockIdx.x;
    const int tid = threadIdx.x;
    const float4 v = ((const float4*)(in + (size_t)row * D))[tid];
    float ss = v.x * v.x + v.y * v.y + v.z * v.z + v.w * v.w;
    #pragma unroll
    for (int off = 32; off >= 1; off >>= 1) ss += __shfl_xor(ss, off, 64);
    __shared__ float red[4];
    const int wave = tid >> 6, lane = tid & 63;
    if (lane == 0) red[wave] = ss;
    __syncthreads();
    const float tot = red[0] + red[1] + red[2] + red[3];
    const float scale = POST_SCALE / fmaxf(sqrtf(tot), 1e-12f);
    bf16x4 o;
    o[0] = (bf16_t)(v.x * scale);
    o[1] = (bf16_t)(v.y * scale);
    o[2] = (bf16_t)(v.z * scale);
    o[3] = (bf16_t)(v.w * scale);
    ((bf16x4*)(out + (size_t)row * D))[tid] = o;
}

// ---------------------------------------------------------------------------
// Kernel 2: barrier-free fused symmetric GEMM.
// Each lane loads its MFMA A/B fragments directly from global (16B coalesced
// per quad-row); no LDS staging, no __syncthreads in the K-loop. Depth-1
// register-rotated software pipeline, fully unrolled (32 steps).
// Lower-triangular tile grid with an XCD/L2 chunk swizzle: chunks of 8 tile
// rows, tj-major inside a chunk, so the 8 blocks of one dispatch round pin
// one A-slab per XCD and share the B-slab.
// ---------------------------------------------------------------------------
__global__ __launch_bounds__(256) void gemm_fused(const bf16_t* __restrict__ E,
                                                  const int* __restrict__ labels,
                                                  float* __restrict__ sumExp,
                                                  float* __restrict__ posSum) {
    __shared__ int labR[TILE], labC[TILE];

    // ---- chunked triangular decode: cum(c) = 32c^2 + 4c ----
    const int b = blockIdx.x;
    int c = (int)((sqrtf(16.0f + 128.0f * (float)b) - 4.0f) * (1.0f / 64.0f));
    while (32 * (c + 1) * (c + 1) + 4 * (c + 1) <= b) ++c;
    while (32 * c * c + 4 * c > b) --c;
    const int r = b - (32 * c * c + 4 * c);
    int ti, tj;
    if (r < 64 * c) {               // rectangular part: tj < 8c, 8 ti's each
        tj = r >> 3;
        ti = 8 * c + (r & 7);
    } else {                        // diagonal 8x8 triangle of the chunk
        int r2 = r - 64 * c;
        int d = 0, off = 0;
        while (off + (8 - d) <= r2) { off += 8 - d; ++d; }
        tj = 8 * c + d;
        ti = tj + (r2 - off);
    }
    const bool isDiag = (ti == tj);

    const int tid     = threadIdx.x;
    const int wave    = tid >> 6;
    const int lane    = tid & 63;
    const int q       = lane >> 4;    // quad (0..3) -> k-block
    const int lr      = lane & 15;    // row/col within 16
    const int waveRow = wave >> 1;    // 2x2 wave grid, 64x64 each
    const int waveCol = wave & 1;
    const int rowStart = ti * TILE;
    const int colStart = tj * TILE;

    if (tid < TILE) labR[tid] = labels[rowStart + tid];
    else            labC[tid - TILE] = labels[colStart + (tid - TILE)];
    __syncthreads();   // labels ready; the only block-wide barrier

    f32x4 acc[4][4];
    #pragma unroll
    for (int i = 0; i < 4; ++i)
        #pragma unroll
        for (int j = 0; j < 4; ++j)
            acc[i][j] = {0.f, 0.f, 0.f, 0.f};

    // Per-lane byte offsets of the 8 fragment streams (A: 4 row groups,
    // B: 4 col groups). Fragment layout for mfma_f32_16x16x32_bf16:
    // lane (q,lr) holds row lr (+16*ri), k = q*8..q*8+7  -> 16B contiguous.
    const char* base = (const char*)E;
    unsigned aOff[4], bOff[4];
    #pragma unroll
    for (int ri = 0; ri < 4; ++ri)
        aOff[ri] = (unsigned)((rowStart + waveRow * 64 + ri * 16 + lr) * (D * 2)
                              + q * 16);
    #pragma unroll
    for (int ci = 0; ci < 4; ++ci)
        bOff[ci] = (unsigned)((colStart + waveCol * 64 + ci * 16 + lr) * (D * 2)
                              + q * 16);

    bf16x8 fa[2][4], fb[2][4];
    #pragma unroll
    for (int ri = 0; ri < 4; ++ri)
        fa[0][ri] = *(const bf16x8*)(base + aOff[ri]);
    #pragma unroll
    for (int ci = 0; ci < 4; ++ci)
        fb[0][ci] = *(const bf16x8*)(base + bOff[ci]);

    #pragma unroll
    for (int s = 0; s < 32; ++s) {
        const int cur = s & 1, nxt = cur ^ 1;
        if (s < 31) {
            const unsigned kb = (unsigned)((s + 1) * 64);  // bytes: 32 k * 2B
            #pragma unroll
            for (int ri = 0; ri < 4; ++ri)
                fa[nxt][ri] = *(const bf16x8*)(base + aOff[ri] + kb);
            #pragma unroll
            for (int ci = 0; ci < 4; ++ci)
                fb[nxt][ci] = *(const bf16x8*)(base + bOff[ci] + kb);
        }
        #pragma unroll
        for (int ri = 0; ri < 4; ++ri)
            #pragma unroll
            for (int ci = 0; ci < 4; ++ci)
                acc[ri][ci] = __builtin_amdgcn_mfma_f32_16x16x32_bf16(
                    fa[cur][ri], fb[cur][ci], acc[ri][ci], 0, 0, 0);
    }

    // ---- epilogue: exp2(acc) -> masked row sums (+ col sums off-diagonal) ----
    // C/D layout: col = lane&15, row = q*4 + e  (m89/m91).
    float colAll[4] = {0.f, 0.f, 0.f, 0.f};
    float colPos[4] = {0.f, 0.f, 0.f, 0.f};
    #pragma unroll
    for (int ri = 0; ri < 4; ++ri) {
        #pragma unroll
        for (int e = 0; e < 4; ++e) {
            const int rloc = waveRow * 64 + ri * 16 + q * 4 + e;
            const int gi   = rowStart + rloc;
            const int li   = labR[rloc];
            float s_all = 0.f, s_pos = 0.f;
            #pragma unroll
            for (int ci = 0; ci < 4; ++ci) {
                const int cloc = waveCol * 64 + ci * 16 + lr;
                const int gj   = colStart + cloc;
#if __has_builtin(__builtin_amdgcn_exp2f)
                const float v = __builtin_amdgcn_exp2f(acc[ri][ci][e]);
#else
                const float v = exp2f(acc[ri][ci][e]);
#endif
                const bool same = (labC[cloc] == li);
                const float vp  = same ? v : 0.f;
                s_all += v;
                if (gi != gj) s_pos += vp;
                if (!isDiag) {          // wave-uniform branch
                    colAll[ci] += v;    // off-diagonal: gi != gj always
                    colPos[ci] += vp;
                }
            }
            #pragma unroll
            for (int off = 1; off < 16; off <<= 1) {
                s_all += __shfl_xor(s_all, off, 64);
                s_pos += __shfl_xor(s_pos, off, 64);
            }
            if (lr == 0) {
                atomicAdd(&sumExp[gi], s_all);
                atomicAdd(&posSum[gi], s_pos);
            }
        }
    }
    if (!isDiag) {
        #pragma unroll
        for (int ci = 0; ci < 4; ++ci) {
            float a = colAll[ci], p = colPos[ci];
            a += __shfl_xor(a, 16, 64);  a += __shfl_xor(a, 32, 64);
            p += __shfl_xor(p, 16, 64);  p += __shfl_xor(p, 32, 64);
            if (q == 0) {
                const int gj = colStart + waveCol * 64 + ci * 16 + lr;
                atomicAdd(&sumExp[gj], a);
                atomicAdd(&posSum[gj], p);
            }
        }
    }
}

// ---------------------------------------------------------------------------
// Kernel 3: loss_i = log(sumExp_i / posSum_i); out = mean(loss).
// ---------------------------------------------------------------------------
__global__ __launch_bounds__(1024) void finalize(const float* __restrict__ sumExp,
                                                 const float* __restrict__ posSum,
                                                 float* __restrict__ out) {
    const int tid = threadIdx.x;
    float s = 0.f;
    #pragma unroll
    for (int i = tid; i < N; i += 1024)
        s += __logf(sumExp[i] / posSum[i]);
    #pragma unroll
    for (int off = 32; off >= 1; off >>= 1) s += __shfl_xor(s, off, 64);
    __shared__ float red[16];
    if ((tid & 63) == 0) red[tid >> 6] = s;
    __syncthreads();
    if (tid == 0) {
        float t = 0.f;
        #pragma unroll
        for (int i = 0; i < 16; ++i) t += red[i];
        out[0] = t / (float)N;
    }
}

extern "C" void kernel_launch(void* const* d_in, const int* in_sizes, int n_in,
                              void* d_out, int out_size, void* d_ws, size_t ws_size,
                              hipStream_t stream) {
    const float* emb    = (const float*)d_in[0];
    const int*   labels = (const int*)d_in[1];
    float* out = (float*)d_out;

    // ws layout: [sumExp: N floats][posSum: N floats][EN: N*D bf16]
    float*  sumExp = (float*)d_ws;
    float*  posSum = sumExp + N;
    bf16_t* EN     = (bf16_t*)((char*)d_ws + (size_t)2 * N * sizeof(float));

    hipMemsetAsync(d_ws, 0, (size_t)2 * N * sizeof(float), stream);

    norm_cast<<<N, 256, 0, stream>>>(emb, EN);

    gemm_fused<<<NBLOCKS, 256, 0, stream>>>(EN, labels, sumExp, posSum);

    finalize<<<1, 1024, 0, stream>>>(sumExp, posSum, out);
}

// Round 4
// 228.082 us; speedup vs baseline: 1.7449x; 1.7449x over previous
//
#include <hip/hip_runtime.h>
#include <hip/hip_bf16.h>
#include <math.h>

#define N 8192
#define D 1024
#define TILE 128
#define BK 64
#define NTILES (N / TILE)                 // 64
#define NBLOCKS (NTILES * (NTILES + 1) / 2)  // 2080 lower-tri tiles

typedef __bf16 bf16_t;
typedef bf16_t bf16x4 __attribute__((ext_vector_type(4)));
typedef bf16_t bf16x8 __attribute__((ext_vector_type(8)));
typedef float f32x4 __attribute__((ext_vector_type(4)));

// exp(sim/T) = exp2(sim/(T*ln2)); fold sqrt(1/(T*ln2)) into the normalized
// embeddings so the epilogue is a bare v_exp_f32 per element.
#define POST_SCALE 4.5398124f

// ---------------------------------------------------------------------------
// Kernel 1: L2-normalize rows, scale, cast to bf16. Also zeroes the
// sumExp/posSum accumulators (blocks 0..63 cover 2N = 16384 floats).
// ---------------------------------------------------------------------------
__global__ __launch_bounds__(256) void norm_cast(const float* __restrict__ in,
                                                 bf16_t* __restrict__ out,
                                                 float* __restrict__ sums) {
    const int row = blockIdx.x;
    const int tid = threadIdx.x;
    if (row < 64) sums[row * 256 + tid] = 0.f;
    const float4 v = ((const float4*)(in + (size_t)row * D))[tid];
    float ss = v.x * v.x + v.y * v.y + v.z * v.z + v.w * v.w;
    #pragma unroll
    for (int off = 32; off >= 1; off >>= 1) ss += __shfl_xor(ss, off, 64);
    __shared__ float red[4];
    const int wave = tid >> 6, lane = tid & 63;
    if (lane == 0) red[wave] = ss;
    __syncthreads();
    const float tot = red[0] + red[1] + red[2] + red[3];
    const float scale = POST_SCALE / fmaxf(sqrtf(tot), 1e-12f);
    bf16x4 o;
    o[0] = (bf16_t)(v.x * scale);
    o[1] = (bf16_t)(v.y * scale);
    o[2] = (bf16_t)(v.z * scale);
    o[3] = (bf16_t)(v.w * scale);
    ((bf16x4*)(out + (size_t)row * D))[tid] = o;
}

// ---------------------------------------------------------------------------
// Kernel 2: fused symmetric GEMM, BK=64, LDS-staged (m97 structure),
// 16 K-iters, 32 MFMA/wave/iter. Swizzle: 16B unit u of row r lives at
// u ^ (r&7); staging permutes the GLOBAL source (128B-coalesced, LDS dest
// stays wave-uniform-linear for global_load_lds). Frag reads then hit all
// 8 bank groups within every 8-lane group -> conflict-free.
// __launch_bounds__(256,4): cap regs at 128 (incl 64 acc AGPRs) -> 4 blk/CU.
// ---------------------------------------------------------------------------
__global__ __launch_bounds__(256, 4) void gemm_fused(
        const bf16_t* __restrict__ E, const int* __restrict__ labels,
        float* __restrict__ sumExp, float* __restrict__ posSum) {
    __shared__ char smem[2 * TILE * BK * 2];   // A: [0,16K), B: [16K,32K)
    __shared__ int labR[TILE], labC[TILE];

    // triangular decode: b -> (ti >= tj)
    const int b = blockIdx.x;
    int ti = (int)((sqrtf(8.0f * (float)b + 1.0f) - 1.0f) * 0.5f);
    while ((ti + 1) * (ti + 2) / 2 <= b) ++ti;
    while (ti * (ti + 1) / 2 > b) --ti;
    const int tj = b - ti * (ti + 1) / 2;
    const bool isDiag = (ti == tj);

    const int tid     = threadIdx.x;
    const int wave    = tid >> 6;
    const int lane    = tid & 63;
    const int q       = lane >> 4;
    const int lr      = lane & 15;
    const int waveRow = wave >> 1;
    const int waveCol = wave & 1;
    const int rowStart = ti * TILE;
    const int colStart = tj * TILE;

    if (tid < TILE) labR[tid] = labels[rowStart + tid];
    else            labC[tid - TILE] = labels[colStart + (tid - TILE)];

    f32x4 acc[4][4];
    #pragma unroll
    for (int i = 0; i < 4; ++i)
        #pragma unroll
        for (int j = 0; j < 4; ++j)
            acc[i][j] = {0.f, 0.f, 0.f, 0.f};

    // Staging source addresses. Pass p covers rows p*32..p*32+31.
    // Lane covers row (wave*8 + lane>>3), unit uc = (lane&7) ^ (lane>>3)
    // (r&7 == lane>>3 since wave*8, p*32 are multiples of 8).
    const int   srow = wave * 8 + (lane >> 3);
    const int   uc   = (lane & 7) ^ (lane >> 3);
    const char* gaBase = (const char*)(E + (size_t)rowStart * D) + srow * (D * 2) + uc * 16;
    const char* gbBase = (const char*)(E + (size_t)colStart * D) + srow * (D * 2) + uc * 16;

    // Frag-read lane addresses (bytes into smem) for k-half h:
    // addr = (row)*128 + ((h*4+q)^(lr&7))*16, row = waveGrp*64 + lr (+ri*16 via imm)
    unsigned aAddr[2], bAddr[2];
    #pragma unroll
    for (int h = 0; h < 2; ++h) {
        const unsigned un = (unsigned)((h * 4 + q) ^ (lr & 7));
        aAddr[h] = (unsigned)((waveRow * 64 + lr) * 128) + un * 16;
        bAddr[h] = (unsigned)(16384 + (waveCol * 64 + lr) * 128) + un * 16;
    }

    for (int it = 0; it < 16; ++it) {
        const unsigned kb = (unsigned)it * 128;   // byte offset within a row
        #pragma unroll
        for (int p = 0; p < 4; ++p) {
            const char* ga = gaBase + kb + p * (32 * D * 2);
            const char* gb = gbBase + kb + p * (32 * D * 2);
            char* la = smem + (p * 256 + wave * 64) * 16;
            char* lb = smem + 16384 + (p * 256 + wave * 64) * 16;
            __builtin_amdgcn_global_load_lds(
                (const __attribute__((address_space(1))) void*)ga,
                (__attribute__((address_space(3))) void*)la, 16, 0, 0);
            __builtin_amdgcn_global_load_lds(
                (const __attribute__((address_space(1))) void*)gb,
                (__attribute__((address_space(3))) void*)lb, 16, 0, 0);
        }
        __syncthreads();

        #pragma unroll
        for (int h = 0; h < 2; ++h) {
            bf16x8 af[4], bfr[4];
            #pragma unroll
            for (int ri = 0; ri < 4; ++ri)
                af[ri] = *(const bf16x8*)(smem + aAddr[h] + ri * 2048);
            #pragma unroll
            for (int ci = 0; ci < 4; ++ci)
                bfr[ci] = *(const bf16x8*)(smem + bAddr[h] + ci * 2048);
            #pragma unroll
            for (int ri = 0; ri < 4; ++ri)
                #pragma unroll
                for (int ci = 0; ci < 4; ++ci)
                    acc[ri][ci] = __builtin_amdgcn_mfma_f32_16x16x32_bf16(
                        af[ri], bfr[ci], acc[ri][ci], 0, 0, 0);
        }
        __syncthreads();
    }

    // ---- epilogue: exp2(acc) -> masked row sums (+ col sums off-diagonal) ----
    // C/D layout: col = lane&15, row = q*4 + e (m89/m91).
    float colAll[4] = {0.f, 0.f, 0.f, 0.f};
    float colPos[4] = {0.f, 0.f, 0.f, 0.f};
    #pragma unroll
    for (int ri = 0; ri < 4; ++ri) {
        #pragma unroll
        for (int e = 0; e < 4; ++e) {
            const int rloc = waveRow * 64 + ri * 16 + q * 4 + e;
            const int gi   = rowStart + rloc;
            const int li   = labR[rloc];
            float s_all = 0.f, s_pos = 0.f;
            #pragma unroll
            for (int ci = 0; ci < 4; ++ci) {
                const int cloc = waveCol * 64 + ci * 16 + lr;
                const int gj   = colStart + cloc;
#if __has_builtin(__builtin_amdgcn_exp2f)
                const float v = __builtin_amdgcn_exp2f(acc[ri][ci][e]);
#else
                const float v = exp2f(acc[ri][ci][e]);
#endif
                const bool same = (labC[cloc] == li);
                const float vp  = same ? v : 0.f;
                s_all += v;
                if (gi != gj) s_pos += vp;
                if (!isDiag) {          // wave-uniform branch
                    colAll[ci] += v;
                    colPos[ci] += vp;
                }
            }
            #pragma unroll
            for (int off = 1; off < 16; off <<= 1) {
                s_all += __shfl_xor(s_all, off, 64);
                s_pos += __shfl_xor(s_pos, off, 64);
            }
            if (lr == 0) {
                atomicAdd(&sumExp[gi], s_all);
                atomicAdd(&posSum[gi], s_pos);
            }
        }
    }
    if (!isDiag) {
        #pragma unroll
        for (int ci = 0; ci < 4; ++ci) {
            float a = colAll[ci], p = colPos[ci];
            a += __shfl_xor(a, 16, 64);  a += __shfl_xor(a, 32, 64);
            p += __shfl_xor(p, 16, 64);  p += __shfl_xor(p, 32, 64);
            if (q == 0) {
                const int gj = colStart + waveCol * 64 + ci * 16 + lr;
                atomicAdd(&sumExp[gj], a);
                atomicAdd(&posSum[gj], p);
            }
        }
    }
}

// ---------------------------------------------------------------------------
// Kernel 3: loss_i = log(sumExp_i / posSum_i); out = mean(loss).
// ---------------------------------------------------------------------------
__global__ __launch_bounds__(1024) void finalize(const float* __restrict__ sumExp,
                                                 const float* __restrict__ posSum,
                                                 float* __restrict__ out) {
    const int tid = threadIdx.x;
    float s = 0.f;
    #pragma unroll
    for (int i = tid; i < N; i += 1024)
        s += __logf(sumExp[i] / posSum[i]);
    #pragma unroll
    for (int off = 32; off >= 1; off >>= 1) s += __shfl_xor(s, off, 64);
    __shared__ float red[16];
    if ((tid & 63) == 0) red[tid >> 6] = s;
    __syncthreads();
    if (tid == 0) {
        float t = 0.f;
        #pragma unroll
        for (int i = 0; i < 16; ++i) t += red[i];
        out[0] = t / (float)N;
    }
}

extern "C" void kernel_launch(void* const* d_in, const int* in_sizes, int n_in,
                              void* d_out, int out_size, void* d_ws, size_t ws_size,
                              hipStream_t stream) {
    const float* emb    = (const float*)d_in[0];
    const int*   labels = (const int*)d_in[1];
    float* out = (float*)d_out;

    // ws layout: [sumExp: N floats][posSum: N floats][EN: N*D bf16]
    float*  sumExp = (float*)d_ws;
    float*  posSum = sumExp + N;
    bf16_t* EN     = (bf16_t*)((char*)d_ws + (size_t)2 * N * sizeof(float));

    norm_cast<<<N, 256, 0, stream>>>(emb, EN, sumExp);

    gemm_fused<<<NBLOCKS, 256, 0, stream>>>(EN, labels, sumExp, posSum);

    finalize<<<1, 1024, 0, stream>>>(sumExp, posSum, out);
}